// Round 2
// baseline (284.048 us; speedup 1.0000x reference)
//
#include <hip/hip_runtime.h>
#include <hip/hip_bf16.h>

typedef __hip_bfloat16 bf16;

#define NB   8
#define NC   64
#define LL   32768
#define KK   5
#define NG   4
#define NDG  2
#define NGD  8        // NG*NDG
#define NCD  8        // NC / NGD
#define NOFF 40       // NGD*KK
#define DWK  7

__device__ __forceinline__ float b2f(bf16 v) { return __bfloat162float(v); }

// ---------------------------------------------------------------------------
// k_prep: permute f32 weights into MAC-friendly layouts.
//  wtA[c*40+o] = pw_off_w[o,c]  (c-major: inner o-loop contiguous)
//  wtM[c*40+o] = pw_m_w[o,c]
//  wtW[(((g*2+d)*8+c)*5+k)*16+o] = weight[g*16+o, d*8+c, k]  (o innermost)
// ---------------------------------------------------------------------------
__global__ __launch_bounds__(256) void k_prep(
    const float* __restrict__ pwA, const float* __restrict__ pwM,
    const float* __restrict__ mw,
    float* __restrict__ wtA, float* __restrict__ wtM, float* __restrict__ wtW)
{
  int idx = blockIdx.x * 256 + threadIdx.x;
  if (idx < 2560) {
    int c = idx / 40, o = idx % 40;
    wtA[idx] = pwA[o * NC + c];
  } else if (idx < 5120) {
    int j = idx - 2560;
    int c = j / 40, o = j % 40;
    wtM[j] = pwM[o * NC + c];
  } else if (idx < 10240) {
    int j = idx - 5120;
    int o = j & 15; int t = j >> 4;
    int k = t % 5;  t /= 5;
    int c = t % 8;  t /= 8;
    int d = t & 1;  int g = t >> 1;
    wtW[j] = mw[((g * 16 + o) * 16 + d * 8 + c) * KK + k];
  }
}

// ---------------------------------------------------------------------------
// k_dwgn: depthwise conv7 + per-channel GroupNorm, BOTH branches, f32 in,
// bf16 h out. One block per (b,c) row; conv recomputed in pass 2.
// ---------------------------------------------------------------------------
__device__ __forceinline__ void load8f(float* dst, const float* __restrict__ row,
                                       int start)
{
  if (start >= 0 && start + 8 <= LL) {
    float4 a = *(const float4*)(row + start);
    float4 b = *(const float4*)(row + start + 4);
    dst[0] = a.x; dst[1] = a.y; dst[2] = a.z; dst[3] = a.w;
    dst[4] = b.x; dst[5] = b.y; dst[6] = b.z; dst[7] = b.w;
  } else {
#pragma unroll
    for (int j = 0; j < 8; ++j) {
      int p = start + j;
      dst[j] = (p >= 0 && p < LL) ? row[p] : 0.f;
    }
  }
}

__global__ __launch_bounds__(256) void k_dwgn(
    const float* __restrict__ x,
    const float* __restrict__ dwAw, const float* __restrict__ dwAb,
    const float* __restrict__ gnAw, const float* __restrict__ gnAb,
    const float* __restrict__ dwMw, const float* __restrict__ dwMb,
    const float* __restrict__ gnMw, const float* __restrict__ gnMb,
    bf16* __restrict__ hA, bf16* __restrict__ hM)
{
  int tid = threadIdx.x;
  int bc  = blockIdx.x;           // b*64 + c
  int c   = bc & 63;
  const float* row = x + (size_t)bc * LL;

  float wa[DWK], wm[DWK];
#pragma unroll
  for (int j = 0; j < DWK; ++j) {
    wa[j] = dwAw[c * DWK + j];
    wm[j] = dwMw[c * DWK + j];
  }
  float ba = dwAb[c], bm = dwMb[c];

  float sa = 0.f, qa = 0.f, sm = 0.f, qm = 0.f;
  for (int it = 0; it < 16; ++it) {
    int m = it * 256 + tid;       // chunk index [0,4096)
    int lb = m * 8;
    float v[24];
    load8f(v + 0,  row, lb - 8);
    load8f(v + 8,  row, lb);
    load8f(v + 16, row, lb + 8);
#pragma unroll
    for (int u = 0; u < 8; ++u) {
      float ya = ba, ym = bm;
#pragma unroll
      for (int j = 0; j < DWK; ++j) {
        float xv = v[5 + u + j];  // x[lb+u-3+j]
        ya += wa[j] * xv;
        ym += wm[j] * xv;
      }
      sa += ya; qa += ya * ya;
      sm += ym; qm += ym * ym;
    }
  }

  __shared__ float4 red[256];
  red[tid] = make_float4(sa, qa, sm, qm);
  __syncthreads();
  for (int s = 128; s > 0; s >>= 1) {
    if (tid < s) {
      float4 a = red[tid], b = red[tid + s];
      red[tid] = make_float4(a.x + b.x, a.y + b.y, a.z + b.z, a.w + b.w);
    }
    __syncthreads();
  }
  __shared__ float prm[4];
  if (tid == 0) {
    float4 r = red[0];
    float mua = r.x / LL, vara = r.y / LL - (r.x / LL) * (r.x / LL);
    float mum = r.z / LL, varm = r.w / LL - (r.z / LL) * (r.z / LL);
    float rsa = rsqrtf(vara + 1e-5f);
    float rsm = rsqrtf(varm + 1e-5f);
    float ga = gnAw[c] * rsa;
    float gm = gnMw[c] * rsm;
    prm[0] = ga; prm[1] = gnAb[c] - mua * ga;
    prm[2] = gm; prm[3] = gnMb[c] - mum * gm;
  }
  __syncthreads();
  float ga = prm[0], ca = prm[1], gm = prm[2], cm = prm[3];

  bf16* oA = hA + (size_t)bc * LL;
  bf16* oM = hM + (size_t)bc * LL;
  for (int it = 0; it < 16; ++it) {
    int m = it * 256 + tid;
    int lb = m * 8;
    float v[24];
    load8f(v + 0,  row, lb - 8);
    load8f(v + 8,  row, lb);
    load8f(v + 16, row, lb + 8);
    float4 packA, packM;
    bf16* pa = (bf16*)&packA;
    bf16* pm = (bf16*)&packM;
#pragma unroll
    for (int u = 0; u < 8; ++u) {
      float ya = ba, ym = bm;
#pragma unroll
      for (int j = 0; j < DWK; ++j) {
        float xv = v[5 + u + j];
        ya += wa[j] * xv;
        ym += wm[j] * xv;
      }
      pa[u] = __float2bfloat16(ya * ga + ca);
      pm[u] = __float2bfloat16(ym * gm + cm);
    }
    *(float4*)(oA + lb) = packA;
    *(float4*)(oM + lb) = packM;
  }
}

// ---------------------------------------------------------------------------
// k_point: 1x1 conv (40x64 matvec per position) for both branches,
// offset scale x4, softmax over K=5 within each of the 8 deform groups.
// One block = (b, 256 consecutive l positions).
// ---------------------------------------------------------------------------
__device__ __forceinline__ void stage_matvec40(
    const bf16* __restrict__ hsrc,   // h + b*64*LL + l0
    const float* __restrict__ wt,    // [c][40] f32
    const float* __restrict__ pb,    // bias [40]
    bf16* hs, int tid, float* acc)
{
#pragma unroll
  for (int i = 0; i < 8; ++i) {
    int fid = i * 256 + tid;
    int c = fid >> 5, q = fid & 31;
    ((float4*)hs)[fid] = *(const float4*)(hsrc + (size_t)c * LL + q * 8);
  }
  __syncthreads();
#pragma unroll
  for (int o = 0; o < NOFF; ++o) acc[o] = pb[o];
  for (int c = 0; c < NC; ++c) {
    float hv = b2f(hs[(c << 8) + tid]);
    const float* wr = wt + c * NOFF;
#pragma unroll
    for (int o4 = 0; o4 < 10; ++o4) {
      float4 w = *(const float4*)(wr + (o4 << 2));
      acc[(o4 << 2) + 0] += w.x * hv;
      acc[(o4 << 2) + 1] += w.y * hv;
      acc[(o4 << 2) + 2] += w.z * hv;
      acc[(o4 << 2) + 3] += w.w * hv;
    }
  }
}

__global__ __launch_bounds__(256) void k_point(
    const bf16* __restrict__ hA, const bf16* __restrict__ hM,
    const float* __restrict__ wtA, const float* __restrict__ wtM,
    const float* __restrict__ pbA, const float* __restrict__ pbM,
    float* __restrict__ offs, float* __restrict__ attn)
{
  __shared__ __align__(16) bf16 hs[NC * 256];   // 32 KB
  int tid = threadIdx.x;
  int b   = blockIdx.x >> 7;
  int l0  = (blockIdx.x & 127) << 8;
  int l   = l0 + tid;
  float acc[NOFF];

  // ---- offset branch ----
  stage_matvec40(hA + (size_t)b * NC * LL + l0, wtA, pbA, hs, tid, acc);
  {
    float* op = offs + (size_t)b * NOFF * LL + l;
#pragma unroll
    for (int o = 0; o < NOFF; ++o) op[(size_t)o * LL] = acc[o] * 4.f;
  }
  __syncthreads();   // all lanes done reading hs before restage

  // ---- mask branch ----
  stage_matvec40(hM + (size_t)b * NC * LL + l0, wtM, pbM, hs, tid, acc);
  {
    float* ap = attn + (size_t)b * NOFF * LL + l;
#pragma unroll
    for (int g8 = 0; g8 < NGD; ++g8) {
      float mx = acc[g8 * 5];
#pragma unroll
      for (int j = 1; j < 5; ++j) mx = fmaxf(mx, acc[g8 * 5 + j]);
      float e[5]; float s = 0.f;
#pragma unroll
      for (int j = 0; j < 5; ++j) { e[j] = __expf(acc[g8 * 5 + j] - mx); s += e[j]; }
      float r = 1.f / s;
#pragma unroll
      for (int j = 0; j < 5; ++j) ap[(size_t)(g8 * 5 + j) * LL] = e[j] * r;
    }
  }
}

// ---------------------------------------------------------------------------
// k_xpose: x (b,c,l) f32 -> xT (b, gd, l, 8) f32: one tap gather = 32 B.
// ---------------------------------------------------------------------------
__global__ __launch_bounds__(256) void k_xpose(
    const float* __restrict__ x, float* __restrict__ xT)
{
  __shared__ __align__(16) float tile[8 * 256];
  int tid = threadIdx.x;
  int l0  = (blockIdx.x & 127) << 8;
  int gd  = (blockIdx.x >> 7) & 7;
  int b   = blockIdx.x >> 10;
  const float* src = x + (size_t)(b * NC + gd * 8) * LL + l0;
#pragma unroll
  for (int i = 0; i < 2; ++i) {
    int fid = i * 256 + tid;          // 512 float4 = 8 rows x 64 float4
    int c = fid >> 6, q = fid & 63;
    ((float4*)tile)[fid] = *(const float4*)(src + (size_t)c * LL + q * 4);
  }
  __syncthreads();
  float4 o0, o1;
  float* ob0 = (float*)&o0;
  float* ob1 = (float*)&o1;
#pragma unroll
  for (int c = 0; c < 4; ++c) ob0[c] = tile[(c << 8) + tid];
#pragma unroll
  for (int c = 0; c < 4; ++c) ob1[c] = tile[((c + 4) << 8) + tid];
  float* dst = xT + ((size_t)(b * 8 + gd) * LL + l0 + tid) * 8;
  *(float4*)(dst + 0) = o0;
  *(float4*)(dst + 4) = o1;
}

// ---------------------------------------------------------------------------
// k_deform: gather + lerp + attn + grouped conv accumulate. f32 out.
// One block = (b, g, 256 l); thread owns all 16 out channels of g.
// ---------------------------------------------------------------------------
__global__ __launch_bounds__(256) void k_deform(
    const float* __restrict__ xT, const float* __restrict__ offs,
    const float* __restrict__ attn, const float* __restrict__ wtW,
    const float* __restrict__ bias, float* __restrict__ out)
{
  int tid  = threadIdx.x;
  int lblk = blockIdx.x & 127;
  int g    = (blockIdx.x >> 7) & 3;
  int b    = blockIdx.x >> 9;
  int l    = (lblk << 8) + tid;

  float acc[16];
#pragma unroll
  for (int o = 0; o < 16; ++o) acc[o] = 0.f;

  const float* offp = offs + (size_t)b * NOFF * LL + l;
  const float* attp = attn + (size_t)b * NOFF * LL + l;

#pragma unroll
  for (int d = 0; d < NDG; ++d) {
    const float* xr = xT + (size_t)(b * 8 + g * 2 + d) * LL * 8;
#pragma unroll
    for (int k = 0; k < KK; ++k) {
      int ch = (g * 2 + d) * KK + k;
      float off = offp[(size_t)ch * LL];
      float at  = attp[(size_t)ch * LL];
      float p   = (float)(l - 2 + k) + off;
      float p0f = floorf(p);
      float w1  = p - p0f;
      int p0 = (int)p0f;
      int p1 = p0 + 1;
      int i0 = min(max(p0, 0), LL - 1);
      int i1 = min(max(p1, 0), LL - 1);
      float f0 = (p0 >= 0 && p0 < LL) ? (1.f - w1) * at : 0.f;
      float f1 = (p1 >= 0 && p1 < LL) ? w1 * at : 0.f;
      float4 r0a = *(const float4*)(xr + (size_t)i0 * 8);
      float4 r0b = *(const float4*)(xr + (size_t)i0 * 8 + 4);
      float4 r1a = *(const float4*)(xr + (size_t)i1 * 8);
      float4 r1b = *(const float4*)(xr + (size_t)i1 * 8 + 4);
      const float* c0 = (const float*)&r0a;   // r0a,r0b contiguous on stack
      const float* c1 = (const float*)&r1a;
      float sv[8];
      sv[0] = r0a.x * f0 + r1a.x * f1;
      sv[1] = r0a.y * f0 + r1a.y * f1;
      sv[2] = r0a.z * f0 + r1a.z * f1;
      sv[3] = r0a.w * f0 + r1a.w * f1;
      sv[4] = r0b.x * f0 + r1b.x * f1;
      sv[5] = r0b.y * f0 + r1b.y * f1;
      sv[6] = r0b.z * f0 + r1b.z * f1;
      sv[7] = r0b.w * f0 + r1b.w * f1;
      (void)c0; (void)c1;
#pragma unroll
      for (int c = 0; c < NCD; ++c) {
        float s = sv[c];
        const float* wpc = wtW + g * 1280 + ((d * 8 + c) * 5 + k) * 16;
#pragma unroll
        for (int o4 = 0; o4 < 4; ++o4) {
          float4 w = *(const float4*)(wpc + (o4 << 2));
          acc[(o4 << 2) + 0] += w.x * s;
          acc[(o4 << 2) + 1] += w.y * s;
          acc[(o4 << 2) + 2] += w.z * s;
          acc[(o4 << 2) + 3] += w.w * s;
        }
      }
    }
  }

  float* op = out + (size_t)(b * NC + g * 16) * LL + l;
#pragma unroll
  for (int o = 0; o < 16; ++o)
    op[(size_t)o * LL] = acc[o] + bias[g * 16 + o];
}

// ---------------------------------------------------------------------------
extern "C" void kernel_launch(void* const* d_in, const int* in_sizes, int n_in,
                              void* d_out, int out_size, void* d_ws, size_t ws_size,
                              hipStream_t stream)
{
  const float* x    = (const float*)d_in[0];
  const float* dwAw = (const float*)d_in[1];
  const float* dwAb = (const float*)d_in[2];
  const float* gnAw = (const float*)d_in[3];
  const float* gnAb = (const float*)d_in[4];
  const float* pwAw = (const float*)d_in[5];
  const float* pwAb = (const float*)d_in[6];
  const float* dwMw = (const float*)d_in[7];
  const float* dwMb = (const float*)d_in[8];
  const float* gnMw = (const float*)d_in[9];
  const float* gnMb = (const float*)d_in[10];
  const float* pwMw = (const float*)d_in[11];
  const float* pwMb = (const float*)d_in[12];
  const float* mw   = (const float*)d_in[13];
  const float* bias = (const float*)d_in[14];
  float* out = (float*)d_out;

  // ws layout, ~151 MB total:
  //   wt arrays: 10240 f32 (40 KB)
  //   hA, hM:    16.78M bf16 each (33.55 MB each) — reused as xT (f32, 67 MB)
  //   offs,attn: 10.49M f32 each (41.9 MB each)
  float* wtA = (float*)d_ws;                    //  2560
  float* wtM = wtA + 2560;                      //  2560
  float* wtW = wtM + 2560;                      //  5120
  bf16* hA   = (bf16*)(wtW + 5120);
  bf16* hM   = hA + (size_t)NB * NC * LL;
  float* offs = (float*)(hM + (size_t)NB * NC * LL);
  float* attn = offs + (size_t)NB * NOFF * LL;
  float* xT  = (float*)hA;   // hA+hM dead after k_point; exactly 67 MB

  hipLaunchKernelGGL(k_prep, dim3(40), dim3(256), 0, stream,
                     pwAw, pwMw, mw, wtA, wtM, wtW);
  hipLaunchKernelGGL(k_dwgn, dim3(NB * NC), dim3(256), 0, stream,
                     x, dwAw, dwAb, gnAw, gnAb, dwMw, dwMb, gnMw, gnMb, hA, hM);
  hipLaunchKernelGGL(k_point, dim3(NB * (LL / 256)), dim3(256), 0, stream,
                     hA, hM, wtA, wtM, pwAb, pwMb, offs, attn);
  hipLaunchKernelGGL(k_xpose, dim3(NB * NGD * (LL / 256)), dim3(256), 0, stream,
                     x, xT);
  hipLaunchKernelGGL(k_deform, dim3(NB * NG * (LL / 256)), dim3(256), 0, stream,
                     xT, offs, attn, wtW, bias, out);
}